// Round 7
// baseline (554.032 us; speedup 1.0000x reference)
//
#include <hip/hip_runtime.h>
#include <math.h>

#define BATCH 2048
#define CIN 14
#define LEN 2048
#define NB 4
#define HID 64
#define NEG 0.01f
#define L2E 1.44269504088896f

typedef __attribute__((ext_vector_type(8))) __bf16 bf16x8;
typedef __attribute__((ext_vector_type(4))) float f32x4;

// ---------------- Kernel A: pool (hierarchical) + conv1d(k=3,pad=1) + LeakyReLU ----------------
__device__ __forceinline__ void conv_bin(const float* __restrict__ P, int ldp, int T,
                                         int bin,
                                         const float* __restrict__ cw,
                                         const float* __restrict__ cb,
                                         float* __restrict__ dst, int tid)
{
    const float* w = cw + (size_t)bin * 4 * CIN * 3;
    const float b0 = cb[bin * 4 + 0];
    const float b1 = cb[bin * 4 + 1];
    const float b2 = cb[bin * 4 + 2];
    const float b3 = cb[bin * 4 + 3];
    for (int t = tid; t < T; t += 256) {
        float a0 = b0, a1 = b1, a2 = b2, a3 = b3;
        for (int ci = 0; ci < CIN; ++ci) {
            float pm = (t > 0)     ? P[ci * ldp + t - 1] : 0.0f;
            float p0 =               P[ci * ldp + t];
            float pp = (t < T - 1) ? P[ci * ldp + t + 1] : 0.0f;
            const float* w0 = w + (0 * CIN + ci) * 3;
            const float* w1 = w + (1 * CIN + ci) * 3;
            const float* w2 = w + (2 * CIN + ci) * 3;
            const float* w3 = w + (3 * CIN + ci) * 3;
            a0 += w0[0] * pm + w0[1] * p0 + w0[2] * pp;
            a1 += w1[0] * pm + w1[1] * p0 + w1[2] * pp;
            a2 += w2[0] * pm + w2[1] * p0 + w2[2] * pp;
            a3 += w3[0] * pm + w3[1] * p0 + w3[2] * pp;
        }
        a0 = (a0 >= 0.0f) ? a0 : NEG * a0;
        a1 = (a1 >= 0.0f) ? a1 : NEG * a1;
        a2 = (a2 >= 0.0f) ? a2 : NEG * a2;
        a3 = (a3 >= 0.0f) ? a3 : NEG * a3;
        *reinterpret_cast<float4*>(dst + (size_t)t * 4) = make_float4(a0, a1, a2, a3);
    }
}

__global__ __launch_bounds__(256) void pool_conv_kernel(
    const float* __restrict__ X, const float* __restrict__ cw,
    const float* __restrict__ cb, float* __restrict__ xc)
{
    __shared__ float Pa[CIN][512];
    __shared__ float Pb[CIN][256];
    const int b = blockIdx.x;
    const int tid = threadIdx.x;

    for (int idx = tid; idx < CIN * 512; idx += 256) {
        int c = idx >> 9, t = idx & 511;
        const float4 v = *reinterpret_cast<const float4*>(X + ((size_t)b * CIN + c) * LEN + 4 * t);
        Pa[c][t] = 0.25f * (v.x + v.y + v.z + v.w);
    }
    __syncthreads();

    conv_bin(&Pa[0][0], 512, 512, 0, cw, cb, xc + (size_t)b * 512 * 4, tid);
    for (int idx = tid; idx < CIN * 256; idx += 256) {
        int c = idx >> 8, t = idx & 255;
        Pb[c][t] = 0.5f * (Pa[c][2 * t] + Pa[c][2 * t + 1]);
    }
    __syncthreads();

    conv_bin(&Pb[0][0], 256, 256, 1, cw, cb, xc + 4194304 + (size_t)b * 256 * 4, tid);
    for (int idx = tid; idx < CIN * 128; idx += 256) {
        int c = idx >> 7, t = idx & 127;
        Pa[c][t] = 0.5f * (Pb[c][2 * t] + Pb[c][2 * t + 1]);
    }
    __syncthreads();

    conv_bin(&Pa[0][0], 512, 128, 2, cw, cb, xc + 6291456 + (size_t)b * 128 * 4, tid);
    for (int idx = tid; idx < CIN * 64; idx += 256) {
        int c = idx >> 6, t = idx & 63;
        Pb[c][t] = 0.5f * (Pa[c][2 * t] + Pa[c][2 * t + 1]);
    }
    __syncthreads();

    conv_bin(&Pb[0][0], 256, 64, 3, cw, cb, xc + 7340032 + (size_t)b * 64 * 4, tid);
}

// ---------------- Kernel B: MFMA LSTM scan + linear head ----------------
// 256 blocks x 512 threads (8 waves). Blocks 0..127: bin 0; 128..255: bins 1,2,3 chained.
// Wave pair (qd, qd+4) both compute quadrant qd's full gate tile (redundant MFMA —
// matrix pipe has headroom), but SPLIT THE UPDATE BY C-ROWS: wave rh=w>>2 updates
// registers r in {2rh, 2rh+1} -> per-wave transcendental work halves (the chain's
// dominant phase at 1 step-serial chain per CU). No inter-wave exchange needed.
// Merged-rcp activations: sig(i)*tanh(g) = (G-1)/[(1+Ei)(G+1)], 8 trans/row vs 10.
// x window prefetched into regs at tw==32 (hides HBM latency under 32 steps).

__global__ __launch_bounds__(512, 1) void lstm_mfma_kernel(
    const float* __restrict__ xc,
    const float* __restrict__ wih, const float* __restrict__ whh,
    const float* __restrict__ bih, const float* __restrict__ bhh,
    const float* __restrict__ lw, const float* __restrict__ lb,
    float* __restrict__ out)
{
    __shared__ __bf16 hbuf[2][2][16][80];   // [pingpong][hi/lo][row][unit]
    __shared__ __bf16 xbuf[16][65][8];      // [batch][step][xhi(4)|xlo(4)]
    __shared__ float  part[256];

    const int tid = threadIdx.x;
    const int w   = tid >> 6;        // wave 0..7
    const int qd  = w & 3;           // unit quadrant
    const int rh  = w >> 2;          // row-half: updates r in {2rh, 2rh+1}
    const int l   = tid & 63;
    const int lm  = l & 15;
    const int lg  = l >> 4;

    const int TS[NB]     = {512, 256, 128, 64};
    const size_t OFF[NB] = {0, 4194304, 6291456, 7340032};

    const bool isBin0 = (blockIdx.x < 128);
    const int b0   = (isBin0 ? blockIdx.x : (blockIdx.x - 128)) * 16;
    const int binS = isBin0 ? 0 : 1;
    const int binE = isBin0 ? 1 : 4;

    for (int bin = binS; bin < binE; ++bin) {
        const int T = TS[bin];
        const int NW = T >> 6;
        const float* xbase = xc + OFF[bin];

        // ---- weights: Whh split fragments + Wih x-tile B-frag + bias ----
        bf16x8 whiF[4][2], wloF[4][2], xwB[4];
        float  bias[4];
        #pragma unroll
        for (int g = 0; g < 4; ++g) {
            const int col = bin * 256 + g * 64 + qd * 16 + lm;
            const float* wr = whh + (size_t)col * 64;
            #pragma unroll
            for (int kt = 0; kt < 2; ++kt) {
                const float* p = wr + kt * 32 + lg * 8;
                const float4 u0 = *reinterpret_cast<const float4*>(p);
                const float4 u1 = *reinterpret_cast<const float4*>(p + 4);
                const float v[8] = {u0.x, u0.y, u0.z, u0.w, u1.x, u1.y, u1.z, u1.w};
                bf16x8 hi8, lo8;
                #pragma unroll
                for (int e = 0; e < 8; ++e) {
                    const __bf16 hb = (__bf16)v[e];
                    hi8[e] = hb;
                    lo8[e] = (__bf16)(v[e] - (float)hb);
                }
                whiF[g][kt] = hi8;
                wloF[g][kt] = lo8;
            }
            const float4 wiv = *reinterpret_cast<const float4*>(wih + (size_t)col * 4);
            bf16x8 xw;
            xw[0] = (__bf16)wiv.x; xw[1] = (__bf16)wiv.y;
            xw[2] = (__bf16)wiv.z; xw[3] = (__bf16)wiv.w;
            xw[4] = xw[0]; xw[5] = xw[1]; xw[6] = xw[2]; xw[7] = xw[3];
            if (lg != 0) {
                #pragma unroll
                for (int e = 0; e < 8; ++e) xw[e] = (__bf16)0.0f;
            }
            xwB[g] = xw;
            bias[g] = bih[col] + bhh[col];
        }

        // ---- prologue: window 0 -> xbuf; zero h pingpong 0 ----
        #pragma unroll
        for (int i = 0; i < 2; ++i) {
            const int idx = tid + i * 512;
            const int bb = idx >> 6, s = idx & 63;
            const float4 xv = *reinterpret_cast<const float4*>(
                xbase + ((size_t)(b0 + bb) * T + s) * 4);
            bf16x8 pk;
            pk[0] = (__bf16)xv.x; pk[1] = (__bf16)xv.y;
            pk[2] = (__bf16)xv.z; pk[3] = (__bf16)xv.w;
            pk[4] = (__bf16)(xv.x - (float)pk[0]);
            pk[5] = (__bf16)(xv.y - (float)pk[1]);
            pk[6] = (__bf16)(xv.z - (float)pk[2]);
            pk[7] = (__bf16)(xv.w - (float)pk[3]);
            *reinterpret_cast<bf16x8*>(&xbuf[bb][s][0]) = pk;
        }
        {
            __bf16* hz = &hbuf[0][0][0][0];
            #pragma unroll
            for (int i = 0; i < 5; ++i) hz[tid + i * 512] = (__bf16)0.0f;
        }
        float c2[2] = {0.0f, 0.0f};

        for (int tb = 0; tb < NW; ++tb) {
            float4 xr[2];
            for (int tw = 0; tw < 64; ++tw) {
                if (tw == 32 && tb + 1 < NW) {
                    #pragma unroll
                    for (int i = 0; i < 2; ++i) {
                        const int idx = tid + i * 512;
                        const int bb = idx >> 6, s = idx & 63;
                        xr[i] = *reinterpret_cast<const float4*>(
                            xbase + ((size_t)(b0 + bb) * T + (tb + 1) * 64 + s) * 4);
                    }
                }
                __syncthreads();   // h(t-1) + x window visible

                const int t = (tb << 6) + tw;
                const int pp = t & 1, pq = pp ^ 1;

                // x-frag first (stable window; its MFMA covers h ds_read latency)
                bf16x8 xf;
                #pragma unroll
                for (int e = 0; e < 8; ++e) xf[e] = (__bf16)0.0f;
                if (lg == 0) xf = *reinterpret_cast<const bf16x8*>(&xbuf[lm][tw][0]);

                bf16x8 zhi[2], zlo[2];
                #pragma unroll
                for (int kt = 0; kt < 2; ++kt) {
                    zhi[kt] = *reinterpret_cast<const bf16x8*>(&hbuf[pp][0][lm][kt * 32 + lg * 8]);
                    zlo[kt] = *reinterpret_cast<const bf16x8*>(&hbuf[pp][1][lm][kt * 32 + lg * 8]);
                }

                // gates: two partial MFMA chains per gate (depth 4 + 3), then merge
                f32x4 acc[4];
                #pragma unroll
                for (int g = 0; g < 4; ++g) {
                    f32x4 a = {bias[g], bias[g], bias[g], bias[g]};
                    f32x4 b = {0.0f, 0.0f, 0.0f, 0.0f};
                    a = __builtin_amdgcn_mfma_f32_16x16x32_bf16(xf,     xwB[g],     a, 0, 0, 0);
                    b = __builtin_amdgcn_mfma_f32_16x16x32_bf16(zlo[1], whiF[g][1], b, 0, 0, 0);
                    a = __builtin_amdgcn_mfma_f32_16x16x32_bf16(zhi[0], whiF[g][0], a, 0, 0, 0);
                    b = __builtin_amdgcn_mfma_f32_16x16x32_bf16(zhi[0], wloF[g][0], b, 0, 0, 0);
                    a = __builtin_amdgcn_mfma_f32_16x16x32_bf16(zhi[1], whiF[g][1], a, 0, 0, 0);
                    b = __builtin_amdgcn_mfma_f32_16x16x32_bf16(zhi[1], wloF[g][1], b, 0, 0, 0);
                    a = __builtin_amdgcn_mfma_f32_16x16x32_bf16(zlo[0], whiF[g][0], a, 0, 0, 0);
                    acc[g] = a + b;
                }

                // update: this wave handles rows r in {2rh, 2rh+1} only (merged-rcp form)
                const int u = qd * 16 + lm;
                #pragma unroll
                for (int j = 0; j < 2; ++j) {
                    const int rj = rh * 2 + j;
                    const float ai = acc[0][rj], af = acc[1][rj];
                    float       ag = acc[2][rj];
                    const float ao = acc[3][rj];
                    ag = fminf(fmaxf(ag, -15.0f), 15.0f);
                    const float Ei = __builtin_amdgcn_exp2f(-L2E * ai);
                    const float Ef = __builtin_amdgcn_exp2f(-L2E * af);
                    const float G  = __builtin_amdgcn_exp2f((2.0f * L2E) * ag);
                    const float Eo = __builtin_amdgcn_exp2f(-L2E * ao);
                    const float ig = (G - 1.0f) * __builtin_amdgcn_rcpf((1.0f + Ei) * (G + 1.0f));
                    c2[j] = fmaf(c2[j], __builtin_amdgcn_rcpf(1.0f + Ef), ig);
                    const float ct = fminf(fmaxf(c2[j], -15.0f), 15.0f);
                    const float C2 = __builtin_amdgcn_exp2f((2.0f * L2E) * ct);
                    const float hv = (C2 - 1.0f) * __builtin_amdgcn_rcpf((1.0f + Eo) * (C2 + 1.0f));
                    const int row = lg * 4 + rj;
                    const __bf16 hb = (__bf16)hv;
                    hbuf[pq][0][row][u] = hb;
                    hbuf[pq][1][row][u] = (__bf16)(hv - (float)hb);
                }
            }
            if (tb + 1 < NW) {
                __syncthreads();   // all reads of this window done
                #pragma unroll
                for (int i = 0; i < 2; ++i) {
                    const int idx = tid + i * 512;
                    const int bb = idx >> 6, s = idx & 63;
                    const float4 xv = xr[i];
                    bf16x8 pk;
                    pk[0] = (__bf16)xv.x; pk[1] = (__bf16)xv.y;
                    pk[2] = (__bf16)xv.z; pk[3] = (__bf16)xv.w;
                    pk[4] = (__bf16)(xv.x - (float)pk[0]);
                    pk[5] = (__bf16)(xv.y - (float)pk[1]);
                    pk[6] = (__bf16)(xv.z - (float)pk[2]);
                    pk[7] = (__bf16)(xv.w - (float)pk[3]);
                    *reinterpret_cast<bf16x8*>(&xbuf[bb][s][0]) = pk;
                }
            }
        }
        __syncthreads();   // final h (pingpong 0, T even) published

        // ---- linear head: out[b][bin] = h[b]·lw[bin] + lb[bin] ----
        {
            if (tid < 256) {
                const int m = tid & 15, up = tid >> 4;
                const float* lwb = lw + bin * HID;
                float s = 0.0f;
                #pragma unroll
                for (int e = 0; e < 4; ++e) {
                    const int uu = up * 4 + e;
                    s = fmaf((float)hbuf[0][0][m][uu] + (float)hbuf[0][1][m][uu], lwb[uu], s);
                }
                part[tid] = s;
            }
            __syncthreads();
            if (tid < 16) {
                float v = lb[bin];
                #pragma unroll
                for (int j = 0; j < 16; ++j) v += part[j * 16 + tid];
                out[(size_t)(b0 + tid) * NB + bin] = v;
            }
            __syncthreads();   // before LDS reuse by next bin
        }
    }
}

extern "C" void kernel_launch(void* const* d_in, const int* in_sizes, int n_in,
                              void* d_out, int out_size, void* d_ws, size_t ws_size,
                              hipStream_t stream) {
    const float* X   = (const float*)d_in[0];
    const float* cw  = (const float*)d_in[1];
    const float* cb  = (const float*)d_in[2];
    const float* wih = (const float*)d_in[3];
    const float* whh = (const float*)d_in[4];
    const float* bih = (const float*)d_in[5];
    const float* bhh = (const float*)d_in[6];
    const float* lw  = (const float*)d_in[7];
    const float* lb  = (const float*)d_in[8];
    float* out = (float*)d_out;
    float* xc  = (float*)d_ws;   // 7,864,320 floats = 31.5 MB

    pool_conv_kernel<<<BATCH, 256, 0, stream>>>(X, cw, cb, xc);
    lstm_mfma_kernel<<<256, 512, 0, stream>>>(xc, wih, whh, bih, bhh, lw, lb, out);
}

// Round 8
// 443.095 us; speedup vs baseline: 1.2504x; 1.2504x over previous
//
#include <hip/hip_runtime.h>
#include <math.h>

#define BATCH 2048
#define CIN 14
#define LEN 2048
#define NB 4
#define HID 64
#define NEG 0.01f
#define L2E 1.44269504088896f

typedef __attribute__((ext_vector_type(8))) __bf16 bf16x8;
typedef __attribute__((ext_vector_type(4))) float f32x4;

// ---------------- Kernel A: pool (hierarchical) + conv1d(k=3,pad=1) + LeakyReLU ----------------
__device__ __forceinline__ void conv_bin(const float* __restrict__ P, int ldp, int T,
                                         int bin,
                                         const float* __restrict__ cw,
                                         const float* __restrict__ cb,
                                         float* __restrict__ dst, int tid)
{
    const float* w = cw + (size_t)bin * 4 * CIN * 3;
    const float b0 = cb[bin * 4 + 0];
    const float b1 = cb[bin * 4 + 1];
    const float b2 = cb[bin * 4 + 2];
    const float b3 = cb[bin * 4 + 3];
    for (int t = tid; t < T; t += 256) {
        float a0 = b0, a1 = b1, a2 = b2, a3 = b3;
        for (int ci = 0; ci < CIN; ++ci) {
            float pm = (t > 0)     ? P[ci * ldp + t - 1] : 0.0f;
            float p0 =               P[ci * ldp + t];
            float pp = (t < T - 1) ? P[ci * ldp + t + 1] : 0.0f;
            const float* w0 = w + (0 * CIN + ci) * 3;
            const float* w1 = w + (1 * CIN + ci) * 3;
            const float* w2 = w + (2 * CIN + ci) * 3;
            const float* w3 = w + (3 * CIN + ci) * 3;
            a0 += w0[0] * pm + w0[1] * p0 + w0[2] * pp;
            a1 += w1[0] * pm + w1[1] * p0 + w1[2] * pp;
            a2 += w2[0] * pm + w2[1] * p0 + w2[2] * pp;
            a3 += w3[0] * pm + w3[1] * p0 + w3[2] * pp;
        }
        a0 = (a0 >= 0.0f) ? a0 : NEG * a0;
        a1 = (a1 >= 0.0f) ? a1 : NEG * a1;
        a2 = (a2 >= 0.0f) ? a2 : NEG * a2;
        a3 = (a3 >= 0.0f) ? a3 : NEG * a3;
        *reinterpret_cast<float4*>(dst + (size_t)t * 4) = make_float4(a0, a1, a2, a3);
    }
}

__global__ __launch_bounds__(256) void pool_conv_kernel(
    const float* __restrict__ X, const float* __restrict__ cw,
    const float* __restrict__ cb, float* __restrict__ xc)
{
    __shared__ float Pa[CIN][512];
    __shared__ float Pb[CIN][256];
    const int b = blockIdx.x;
    const int tid = threadIdx.x;

    for (int idx = tid; idx < CIN * 512; idx += 256) {
        int c = idx >> 9, t = idx & 511;
        const float4 v = *reinterpret_cast<const float4*>(X + ((size_t)b * CIN + c) * LEN + 4 * t);
        Pa[c][t] = 0.25f * (v.x + v.y + v.z + v.w);
    }
    __syncthreads();

    conv_bin(&Pa[0][0], 512, 512, 0, cw, cb, xc + (size_t)b * 512 * 4, tid);
    for (int idx = tid; idx < CIN * 256; idx += 256) {
        int c = idx >> 8, t = idx & 255;
        Pb[c][t] = 0.5f * (Pa[c][2 * t] + Pa[c][2 * t + 1]);
    }
    __syncthreads();

    conv_bin(&Pb[0][0], 256, 256, 1, cw, cb, xc + 4194304 + (size_t)b * 256 * 4, tid);
    for (int idx = tid; idx < CIN * 128; idx += 256) {
        int c = idx >> 7, t = idx & 127;
        Pa[c][t] = 0.5f * (Pb[c][2 * t] + Pb[c][2 * t + 1]);
    }
    __syncthreads();

    conv_bin(&Pa[0][0], 512, 128, 2, cw, cb, xc + 6291456 + (size_t)b * 128 * 4, tid);
    for (int idx = tid; idx < CIN * 64; idx += 256) {
        int c = idx >> 6, t = idx & 63;
        Pb[c][t] = 0.5f * (Pa[c][2 * t] + Pa[c][2 * t + 1]);
    }
    __syncthreads();

    conv_bin(&Pb[0][0], 256, 64, 3, cw, cb, xc + 7340032 + (size_t)b * 64 * 4, tid);
}

// ---------------- Kernel B: MFMA LSTM scan + linear head (GATE-SPLIT, 8 waves) ----------------
// 256 blocks x 512 threads. Blocks 0..127: bin 0; 128..255: bins 1,2,3 chained.
// Wave (qd, gh): quadrant qd (units qd*16..+15); gh=0 computes gates {i,f}, gh=1 {g,o}.
// NO duplication: 14 MFMAs/wave (28/SIMD, same as round 6) but per-wave stream halves,
// and 2 lockstep waves/SIMD interleave inside each phase to fill dependency bubbles.
// Exchange: gh=0 sends sig(i),sig(f) rows{2,3}; gh=1 sends tanh(g),sig(o) rows{0,1}
// (one float4/lane each way). Each wave then updates 2 rows and writes h hi/lo.
// exp2 scaling folded into weights (+2*L2E for g, -L2E for i,f,o); NaN-safe
// 1-2*rcp(1+exp2(.)) forms (no clamps; rcp(Inf)=0 handles saturation exactly).

__global__ __launch_bounds__(512, 1) void lstm_mfma_kernel(
    const float* __restrict__ xc,
    const float* __restrict__ wih, const float* __restrict__ whh,
    const float* __restrict__ bih, const float* __restrict__ bhh,
    const float* __restrict__ lw, const float* __restrict__ lb,
    float* __restrict__ out)
{
    __shared__ __bf16 hbuf[2][2][16][80];   // [pingpong][hi/lo][row][unit]
    __shared__ __bf16 xbuf[16][65][8];      // [batch][step][xhi(4)|xlo(4)]
    __shared__ float  exch[4][2][64][4];    // [qd][src gh][lane][4]
    __shared__ float  part[256];

    const int tid = threadIdx.x;
    const int w   = tid >> 6;        // wave 0..7
    const int qd  = w & 3;           // unit quadrant
    const int gh  = w >> 2;          // gate half: 0={i,f}, 1={g,o}
    const int l   = tid & 63;
    const int lm  = l & 15;
    const int lg  = l >> 4;

    const int TS[NB]     = {512, 256, 128, 64};
    const size_t OFF[NB] = {0, 4194304, 6291456, 7340032};

    const bool isBin0 = (blockIdx.x < 128);
    const int b0   = (isBin0 ? blockIdx.x : (blockIdx.x - 128)) * 16;
    const int binS = isBin0 ? 0 : 1;
    const int binE = isBin0 ? 1 : 4;

    for (int bin = binS; bin < binE; ++bin) {
        const int T = TS[bin];
        const int NW = T >> 6;
        const float* xbase = xc + OFF[bin];

        // ---- weights for this wave's TWO gates, pre-scaled for exp2 ----
        bf16x8 whiF[2][2], wloF[2][2], xwB[2];
        float  bias[2];
        #pragma unroll
        for (int gg = 0; gg < 2; ++gg) {
            const int gate = gh * 2 + gg;                 // 0=i,1=f,2=g,3=o
            const float sc = (gate == 2) ? (2.0f * L2E) : (-L2E);
            const int col = bin * 256 + gate * 64 + qd * 16 + lm;
            const float* wr = whh + (size_t)col * 64;
            #pragma unroll
            for (int kt = 0; kt < 2; ++kt) {
                const float* p = wr + kt * 32 + lg * 8;
                const float4 u0 = *reinterpret_cast<const float4*>(p);
                const float4 u1 = *reinterpret_cast<const float4*>(p + 4);
                const float v[8] = {sc * u0.x, sc * u0.y, sc * u0.z, sc * u0.w,
                                    sc * u1.x, sc * u1.y, sc * u1.z, sc * u1.w};
                bf16x8 hi8, lo8;
                #pragma unroll
                for (int e = 0; e < 8; ++e) {
                    const __bf16 hb = (__bf16)v[e];
                    hi8[e] = hb;
                    lo8[e] = (__bf16)(v[e] - (float)hb);
                }
                whiF[gg][kt] = hi8;
                wloF[gg][kt] = lo8;
            }
            const float4 wiv = *reinterpret_cast<const float4*>(wih + (size_t)col * 4);
            bf16x8 xw;
            xw[0] = (__bf16)(sc * wiv.x); xw[1] = (__bf16)(sc * wiv.y);
            xw[2] = (__bf16)(sc * wiv.z); xw[3] = (__bf16)(sc * wiv.w);
            xw[4] = xw[0]; xw[5] = xw[1]; xw[6] = xw[2]; xw[7] = xw[3];
            if (lg != 0) {
                #pragma unroll
                for (int e = 0; e < 8; ++e) xw[e] = (__bf16)0.0f;
            }
            xwB[gg] = xw;
            bias[gg] = (bih[col] + bhh[col]) * sc;
        }

        // ---- prologue: window 0 -> xbuf; zero h pingpong 0 ----
        #pragma unroll
        for (int i = 0; i < 2; ++i) {
            const int idx = tid + i * 512;
            const int bb = idx >> 6, s = idx & 63;
            const float4 xv = *reinterpret_cast<const float4*>(
                xbase + ((size_t)(b0 + bb) * T + s) * 4);
            bf16x8 pk;
            pk[0] = (__bf16)xv.x; pk[1] = (__bf16)xv.y;
            pk[2] = (__bf16)xv.z; pk[3] = (__bf16)xv.w;
            pk[4] = (__bf16)(xv.x - (float)pk[0]);
            pk[5] = (__bf16)(xv.y - (float)pk[1]);
            pk[6] = (__bf16)(xv.z - (float)pk[2]);
            pk[7] = (__bf16)(xv.w - (float)pk[3]);
            *reinterpret_cast<bf16x8*>(&xbuf[bb][s][0]) = pk;
        }
        {
            __bf16* hz = &hbuf[0][0][0][0];
            #pragma unroll
            for (int i = 0; i < 5; ++i) hz[tid + i * 512] = (__bf16)0.0f;
        }
        float c2[2] = {0.0f, 0.0f};

        for (int tb = 0; tb < NW; ++tb) {
            float4 xr[2];
            #pragma unroll 2
            for (int tw = 0; tw < 64; ++tw) {
                __syncthreads();   // S1: h(t-1) + x window visible; exch free

                const int pp = tw & 1, pq = pp ^ 1;

                bf16x8 xf;
                #pragma unroll
                for (int e = 0; e < 8; ++e) xf[e] = (__bf16)0.0f;
                if (lg == 0) xf = *reinterpret_cast<const bf16x8*>(&xbuf[lm][tw][0]);

                bf16x8 zhi[2], zlo[2];
                #pragma unroll
                for (int kt = 0; kt < 2; ++kt) {
                    zhi[kt] = *reinterpret_cast<const bf16x8*>(&hbuf[pp][0][lm][kt * 32 + lg * 8]);
                    zlo[kt] = *reinterpret_cast<const bf16x8*>(&hbuf[pp][1][lm][kt * 32 + lg * 8]);
                }

                if (tw == 32 && tb + 1 < NW) {
                    #pragma unroll
                    for (int i = 0; i < 2; ++i) {
                        const int idx = tid + i * 512;
                        const int bb = idx >> 6, s = idx & 63;
                        xr[i] = *reinterpret_cast<const float4*>(
                            xbase + ((size_t)(b0 + bb) * T + (tb + 1) * 64 + s) * 4);
                    }
                }

                // ---- 7 MFMAs per gate, two gates, split a/b chains ----
                f32x4 acc[2];
                #pragma unroll
                for (int gg = 0; gg < 2; ++gg) {
                    f32x4 a = {bias[gg], bias[gg], bias[gg], bias[gg]};
                    f32x4 b = {0.0f, 0.0f, 0.0f, 0.0f};
                    a = __builtin_amdgcn_mfma_f32_16x16x32_bf16(xf,     xwB[gg],      a, 0, 0, 0);
                    b = __builtin_amdgcn_mfma_f32_16x16x32_bf16(zlo[0], whiF[gg][0],  b, 0, 0, 0);
                    a = __builtin_amdgcn_mfma_f32_16x16x32_bf16(zhi[0], whiF[gg][0],  a, 0, 0, 0);
                    b = __builtin_amdgcn_mfma_f32_16x16x32_bf16(zlo[1], whiF[gg][1],  b, 0, 0, 0);
                    a = __builtin_amdgcn_mfma_f32_16x16x32_bf16(zhi[1], whiF[gg][1],  a, 0, 0, 0);
                    b = __builtin_amdgcn_mfma_f32_16x16x32_bf16(zhi[0], wloF[gg][0],  b, 0, 0, 0);
                    a = __builtin_amdgcn_mfma_f32_16x16x32_bf16(zhi[1], wloF[gg][1],  a, 0, 0, 0);
                    acc[gg] = a + b;
                }

                // ---- own-gate activations (all 4 rows), NaN-safe rcp forms ----
                float v0[4], v1[4];
                if (gh == 0) {
                    #pragma unroll
                    for (int r = 0; r < 4; ++r) {
                        v0[r] = __builtin_amdgcn_rcpf(1.0f + __builtin_amdgcn_exp2f(acc[0][r]));  // sig(i)
                        v1[r] = __builtin_amdgcn_rcpf(1.0f + __builtin_amdgcn_exp2f(acc[1][r]));  // sig(f)
                    }
                    *reinterpret_cast<float4*>(&exch[qd][0][l][0]) =
                        make_float4(v0[2], v1[2], v0[3], v1[3]);
                } else {
                    #pragma unroll
                    for (int r = 0; r < 4; ++r) {
                        v0[r] = fmaf(-2.0f,
                                 __builtin_amdgcn_rcpf(1.0f + __builtin_amdgcn_exp2f(acc[0][r])),
                                 1.0f);                                                            // tanh(g)
                        v1[r] = __builtin_amdgcn_rcpf(1.0f + __builtin_amdgcn_exp2f(acc[1][r]));  // sig(o)
                    }
                    *reinterpret_cast<float4*>(&exch[qd][1][l][0]) =
                        make_float4(v0[0], v1[0], v0[1], v1[1]);
                }
                __syncthreads();   // S2: exchange visible

                const float4 pv = *reinterpret_cast<const float4*>(&exch[qd][gh ^ 1][l][0]);
                const int u = qd * 16 + lm;
                #pragma unroll
                for (int j = 0; j < 2; ++j) {
                    float gi, gf, gg_, go;
                    int row;
                    if (gh == 0) {          // my rows: lg*4 + {0,1}; partner sent tg,so
                        gi = v0[j]; gf = v1[j];
                        gg_ = (j == 0) ? pv.x : pv.z;
                        go  = (j == 0) ? pv.y : pv.w;
                        row = lg * 4 + j;
                    } else {                // my rows: lg*4 + {2,3}; partner sent si,sf
                        gi = (j == 0) ? pv.x : pv.z;
                        gf = (j == 0) ? pv.y : pv.w;
                        gg_ = v0[2 + j]; go = v1[2 + j];
                        row = lg * 4 + 2 + j;
                    }
                    c2[j] = fmaf(gf, c2[j], gi * gg_);
                    const float Ct = __builtin_amdgcn_exp2f((2.0f * L2E) * c2[j]);
                    const float tc = fmaf(-2.0f, __builtin_amdgcn_rcpf(1.0f + Ct), 1.0f);
                    const float hv = go * tc;
                    const __bf16 hb = (__bf16)hv;
                    hbuf[pq][0][row][u] = hb;
                    hbuf[pq][1][row][u] = (__bf16)(hv - (float)hb);
                }
            }
            if (tb + 1 < NW) {
                // safe: all xbuf reads of this window happened before the last S2
                #pragma unroll
                for (int i = 0; i < 2; ++i) {
                    const int idx = tid + i * 512;
                    const int bb = idx >> 6, s = idx & 63;
                    const float4 xv = xr[i];
                    bf16x8 pk;
                    pk[0] = (__bf16)xv.x; pk[1] = (__bf16)xv.y;
                    pk[2] = (__bf16)xv.z; pk[3] = (__bf16)xv.w;
                    pk[4] = (__bf16)(xv.x - (float)pk[0]);
                    pk[5] = (__bf16)(xv.y - (float)pk[1]);
                    pk[6] = (__bf16)(xv.z - (float)pk[2]);
                    pk[7] = (__bf16)(xv.w - (float)pk[3]);
                    *reinterpret_cast<bf16x8*>(&xbuf[bb][s][0]) = pk;
                }
            }
        }
        __syncthreads();   // final h (pingpong 0, T even) published

        // ---- linear head: out[b][bin] = h[b]·lw[bin] + lb[bin] ----
        {
            if (tid < 256) {
                const int m = tid & 15, up = tid >> 4;
                const float* lwb = lw + bin * HID;
                float s = 0.0f;
                #pragma unroll
                for (int e = 0; e < 4; ++e) {
                    const int uu = up * 4 + e;
                    s = fmaf((float)hbuf[0][0][m][uu] + (float)hbuf[0][1][m][uu], lwb[uu], s);
                }
                part[tid] = s;
            }
            __syncthreads();
            if (tid < 16) {
                float v = lb[bin];
                #pragma unroll
                for (int j = 0; j < 16; ++j) v += part[j * 16 + tid];
                out[(size_t)(b0 + tid) * NB + bin] = v;
            }
            __syncthreads();   // before LDS reuse by next bin
        }
    }
}

extern "C" void kernel_launch(void* const* d_in, const int* in_sizes, int n_in,
                              void* d_out, int out_size, void* d_ws, size_t ws_size,
                              hipStream_t stream) {
    const float* X   = (const float*)d_in[0];
    const float* cw  = (const float*)d_in[1];
    const float* cb  = (const float*)d_in[2];
    const float* wih = (const float*)d_in[3];
    const float* whh = (const float*)d_in[4];
    const float* bih = (const float*)d_in[5];
    const float* bhh = (const float*)d_in[6];
    const float* lw  = (const float*)d_in[7];
    const float* lb  = (const float*)d_in[8];
    float* out = (float*)d_out;
    float* xc  = (float*)d_ws;   // 7,864,320 floats = 31.5 MB

    pool_conv_kernel<<<BATCH, 256, 0, stream>>>(X, cw, cb, xc);
    lstm_mfma_kernel<<<256, 512, 0, stream>>>(xc, wih, whh, bih, bhh, lw, lb, out);
}

// Round 9
// 416.551 us; speedup vs baseline: 1.3300x; 1.0637x over previous
//
#include <hip/hip_runtime.h>
#include <math.h>

#define BATCH 2048
#define CIN 14
#define LEN 2048
#define NB 4
#define HID 64
#define NEG 0.01f
#define L2E 1.44269504088896f

typedef __attribute__((ext_vector_type(8))) __bf16 bf16x8;
typedef __attribute__((ext_vector_type(4))) float f32x4;

// ---------------- Kernel A: pool (hierarchical) + conv1d(k=3,pad=1) + LeakyReLU ----------------
__device__ __forceinline__ void conv_bin(const float* __restrict__ P, int ldp, int T,
                                         int bin,
                                         const float* __restrict__ cw,
                                         const float* __restrict__ cb,
                                         float* __restrict__ dst, int tid)
{
    const float* w = cw + (size_t)bin * 4 * CIN * 3;
    const float b0 = cb[bin * 4 + 0];
    const float b1 = cb[bin * 4 + 1];
    const float b2 = cb[bin * 4 + 2];
    const float b3 = cb[bin * 4 + 3];
    for (int t = tid; t < T; t += 256) {
        float a0 = b0, a1 = b1, a2 = b2, a3 = b3;
        for (int ci = 0; ci < CIN; ++ci) {
            float pm = (t > 0)     ? P[ci * ldp + t - 1] : 0.0f;
            float p0 =               P[ci * ldp + t];
            float pp = (t < T - 1) ? P[ci * ldp + t + 1] : 0.0f;
            const float* w0 = w + (0 * CIN + ci) * 3;
            const float* w1 = w + (1 * CIN + ci) * 3;
            const float* w2 = w + (2 * CIN + ci) * 3;
            const float* w3 = w + (3 * CIN + ci) * 3;
            a0 += w0[0] * pm + w0[1] * p0 + w0[2] * pp;
            a1 += w1[0] * pm + w1[1] * p0 + w1[2] * pp;
            a2 += w2[0] * pm + w2[1] * p0 + w2[2] * pp;
            a3 += w3[0] * pm + w3[1] * p0 + w3[2] * pp;
        }
        a0 = (a0 >= 0.0f) ? a0 : NEG * a0;
        a1 = (a1 >= 0.0f) ? a1 : NEG * a1;
        a2 = (a2 >= 0.0f) ? a2 : NEG * a2;
        a3 = (a3 >= 0.0f) ? a3 : NEG * a3;
        *reinterpret_cast<float4*>(dst + (size_t)t * 4) = make_float4(a0, a1, a2, a3);
    }
}

__global__ __launch_bounds__(256) void pool_conv_kernel(
    const float* __restrict__ X, const float* __restrict__ cw,
    const float* __restrict__ cb, float* __restrict__ xc)
{
    __shared__ float Pa[CIN][512];
    __shared__ float Pb[CIN][256];
    const int b = blockIdx.x;
    const int tid = threadIdx.x;

    for (int idx = tid; idx < CIN * 512; idx += 256) {
        int c = idx >> 9, t = idx & 511;
        const float4 v = *reinterpret_cast<const float4*>(X + ((size_t)b * CIN + c) * LEN + 4 * t);
        Pa[c][t] = 0.25f * (v.x + v.y + v.z + v.w);
    }
    __syncthreads();

    conv_bin(&Pa[0][0], 512, 512, 0, cw, cb, xc + (size_t)b * 512 * 4, tid);
    for (int idx = tid; idx < CIN * 256; idx += 256) {
        int c = idx >> 8, t = idx & 255;
        Pb[c][t] = 0.5f * (Pa[c][2 * t] + Pa[c][2 * t + 1]);
    }
    __syncthreads();

    conv_bin(&Pb[0][0], 256, 256, 1, cw, cb, xc + 4194304 + (size_t)b * 256 * 4, tid);
    for (int idx = tid; idx < CIN * 128; idx += 256) {
        int c = idx >> 7, t = idx & 127;
        Pa[c][t] = 0.5f * (Pb[c][2 * t] + Pb[c][2 * t + 1]);
    }
    __syncthreads();

    conv_bin(&Pa[0][0], 512, 128, 2, cw, cb, xc + 6291456 + (size_t)b * 128 * 4, tid);
    for (int idx = tid; idx < CIN * 64; idx += 256) {
        int c = idx >> 6, t = idx & 63;
        Pb[c][t] = 0.5f * (Pa[c][2 * t] + Pa[c][2 * t + 1]);
    }
    __syncthreads();

    conv_bin(&Pb[0][0], 256, 64, 3, cw, cb, xc + 7340032 + (size_t)b * 64 * 4, tid);
}

// ---------------- Kernel B: MFMA LSTM scan + linear head ----------------
// Round-6 structure (4 waves x 16 batch, wave = unit quadrant, 1 barrier/step,
// 28 MFMA + 40 trans per wave) with the allocator fixed:
//   amdgpu_waves_per_eu(1,1): this kernel runs exactly 1 wave/SIMD (1 block/CU by
//   LDS+grid design), so give the allocator the full VGPR budget -> weights,
//   biases, and LDS addresses stay RESIDENT instead of being rematerialized
//   every step (r6 VGPR=96 < ~140 live values => reload VALU was ~half the wall).
// + unroll-2 step loop (compile-time ping-pong addresses)
// + exp2-prescaled weights (no per-gate scale muls) with NaN-safe rcp forms.

__global__ __launch_bounds__(256)
__attribute__((amdgpu_waves_per_eu(1, 1)))
void lstm_mfma_kernel(
    const float* __restrict__ xc,
    const float* __restrict__ wih, const float* __restrict__ whh,
    const float* __restrict__ bih, const float* __restrict__ bhh,
    const float* __restrict__ lw, const float* __restrict__ lb,
    float* __restrict__ out)
{
    __shared__ __bf16 hbuf[2][2][16][80];   // [pingpong][hi/lo][row][unit]
    __shared__ __bf16 xbuf[16][65][8];      // [batch][step][xhi(4)|xlo(4)]
    __shared__ float  part[256];

    const int tid = threadIdx.x;
    const int w   = tid >> 6;        // wave = unit quadrant
    const int l   = tid & 63;
    const int lm  = l & 15;
    const int lg  = l >> 4;

    const int TS[NB]     = {512, 256, 128, 64};
    const size_t OFF[NB] = {0, 4194304, 6291456, 7340032};

    const bool isBin0 = (blockIdx.x < 128);
    const int b0   = (isBin0 ? blockIdx.x : (blockIdx.x - 128)) * 16;
    const int binS = isBin0 ? 0 : 1;
    const int binE = isBin0 ? 1 : 4;

    for (int bin = binS; bin < binE; ++bin) {
        const int T = TS[bin];
        const int NW = T >> 6;
        const float* xbase = xc + OFF[bin];

        // ---- weights: Whh split fragments + Wih x-tile B-frag + bias, exp2-prescaled ----
        bf16x8 whiF[4][2], wloF[4][2], xwB[4];
        float  bias[4];
        #pragma unroll
        for (int g = 0; g < 4; ++g) {
            const float sc = (g == 2) ? (2.0f * L2E) : (-L2E);
            const int col = bin * 256 + g * 64 + w * 16 + lm;
            const float* wr = whh + (size_t)col * 64;
            #pragma unroll
            for (int kt = 0; kt < 2; ++kt) {
                const float* p = wr + kt * 32 + lg * 8;
                const float4 u0 = *reinterpret_cast<const float4*>(p);
                const float4 u1 = *reinterpret_cast<const float4*>(p + 4);
                const float v[8] = {sc * u0.x, sc * u0.y, sc * u0.z, sc * u0.w,
                                    sc * u1.x, sc * u1.y, sc * u1.z, sc * u1.w};
                bf16x8 hi8, lo8;
                #pragma unroll
                for (int e = 0; e < 8; ++e) {
                    const __bf16 hb = (__bf16)v[e];
                    hi8[e] = hb;
                    lo8[e] = (__bf16)(v[e] - (float)hb);
                }
                whiF[g][kt] = hi8;
                wloF[g][kt] = lo8;
            }
            const float4 wiv = *reinterpret_cast<const float4*>(wih + (size_t)col * 4);
            bf16x8 xw;
            xw[0] = (__bf16)(sc * wiv.x); xw[1] = (__bf16)(sc * wiv.y);
            xw[2] = (__bf16)(sc * wiv.z); xw[3] = (__bf16)(sc * wiv.w);
            xw[4] = xw[0]; xw[5] = xw[1]; xw[6] = xw[2]; xw[7] = xw[3];
            if (lg != 0) {
                #pragma unroll
                for (int e = 0; e < 8; ++e) xw[e] = (__bf16)0.0f;
            }
            xwB[g] = xw;
            bias[g] = (bih[col] + bhh[col]) * sc;
        }

        // ---- prologue: window 0 -> xbuf; zero h pingpong 0 ----
        #pragma unroll
        for (int i = 0; i < 4; ++i) {
            const int idx = tid + i * 256;
            const int bb = idx >> 6, s = idx & 63;
            const float4 xv = *reinterpret_cast<const float4*>(
                xbase + ((size_t)(b0 + bb) * T + s) * 4);
            bf16x8 pk;
            pk[0] = (__bf16)xv.x; pk[1] = (__bf16)xv.y;
            pk[2] = (__bf16)xv.z; pk[3] = (__bf16)xv.w;
            pk[4] = (__bf16)(xv.x - (float)pk[0]);
            pk[5] = (__bf16)(xv.y - (float)pk[1]);
            pk[6] = (__bf16)(xv.z - (float)pk[2]);
            pk[7] = (__bf16)(xv.w - (float)pk[3]);
            *reinterpret_cast<bf16x8*>(&xbuf[bb][s][0]) = pk;
        }
        {
            __bf16* hz = &hbuf[0][0][0][0];
            #pragma unroll
            for (int i = 0; i < 10; ++i) hz[tid + i * 256] = (__bf16)0.0f;
        }
        float c4[4] = {0.0f, 0.0f, 0.0f, 0.0f};

        for (int tb = 0; tb < NW; ++tb) {
            float4 xr[4];
            #pragma unroll 2
            for (int tw = 0; tw < 64; ++tw) {
                if (tw == 32 && tb + 1 < NW) {
                    #pragma unroll
                    for (int i = 0; i < 4; ++i) {
                        const int idx = tid + i * 256;
                        const int bb = idx >> 6, s = idx & 63;
                        xr[i] = *reinterpret_cast<const float4*>(
                            xbase + ((size_t)(b0 + bb) * T + (tb + 1) * 64 + s) * 4);
                    }
                }
                __syncthreads();   // h(t-1) + x window visible

                const int pp = tw & 1, pq = pp ^ 1;   // compile-time under unroll 2

                bf16x8 xf;
                #pragma unroll
                for (int e = 0; e < 8; ++e) xf[e] = (__bf16)0.0f;
                if (lg == 0) xf = *reinterpret_cast<const bf16x8*>(&xbuf[lm][tw][0]);

                bf16x8 zhi[2], zlo[2];
                #pragma unroll
                for (int kt = 0; kt < 2; ++kt) {
                    zhi[kt] = *reinterpret_cast<const bf16x8*>(&hbuf[pp][0][lm][kt * 32 + lg * 8]);
                    zlo[kt] = *reinterpret_cast<const bf16x8*>(&hbuf[pp][1][lm][kt * 32 + lg * 8]);
                }

                // gates: bias + x-tile + split-bf16 h-recurrence (two partial chains)
                f32x4 acc[4];
                #pragma unroll
                for (int g = 0; g < 4; ++g) {
                    f32x4 a = {bias[g], bias[g], bias[g], bias[g]};
                    f32x4 b = {0.0f, 0.0f, 0.0f, 0.0f};
                    a = __builtin_amdgcn_mfma_f32_16x16x32_bf16(xf,     xwB[g],      a, 0, 0, 0);
                    b = __builtin_amdgcn_mfma_f32_16x16x32_bf16(zlo[0], whiF[g][0],  b, 0, 0, 0);
                    a = __builtin_amdgcn_mfma_f32_16x16x32_bf16(zhi[0], whiF[g][0],  a, 0, 0, 0);
                    b = __builtin_amdgcn_mfma_f32_16x16x32_bf16(zlo[1], whiF[g][1],  b, 0, 0, 0);
                    a = __builtin_amdgcn_mfma_f32_16x16x32_bf16(zhi[1], whiF[g][1],  a, 0, 0, 0);
                    b = __builtin_amdgcn_mfma_f32_16x16x32_bf16(zhi[0], wloF[g][0],  b, 0, 0, 0);
                    a = __builtin_amdgcn_mfma_f32_16x16x32_bf16(zhi[1], wloF[g][1],  a, 0, 0, 0);
                    acc[g] = a + b;
                }

                // in-register cell update (NaN-safe rcp forms; weights pre-scaled)
                const int u = w * 16 + lm;
                #pragma unroll
                for (int r = 0; r < 4; ++r) {
                    const float si = __builtin_amdgcn_rcpf(1.0f + __builtin_amdgcn_exp2f(acc[0][r]));
                    const float sf = __builtin_amdgcn_rcpf(1.0f + __builtin_amdgcn_exp2f(acc[1][r]));
                    const float tg = fmaf(-2.0f,
                        __builtin_amdgcn_rcpf(1.0f + __builtin_amdgcn_exp2f(acc[2][r])), 1.0f);
                    const float so = __builtin_amdgcn_rcpf(1.0f + __builtin_amdgcn_exp2f(acc[3][r]));
                    c4[r] = fmaf(sf, c4[r], si * tg);
                    const float tc = fmaf(-2.0f,
                        __builtin_amdgcn_rcpf(1.0f + __builtin_amdgcn_exp2f((2.0f * L2E) * c4[r])), 1.0f);
                    const float hv = so * tc;
                    const int row = lg * 4 + r;
                    const __bf16 hb = (__bf16)hv;
                    hbuf[pq][0][row][u] = hb;
                    hbuf[pq][1][row][u] = (__bf16)(hv - (float)hb);
                }
            }
            if (tb + 1 < NW) {
                __syncthreads();   // all reads of this x window done
                #pragma unroll
                for (int i = 0; i < 4; ++i) {
                    const int idx = tid + i * 256;
                    const int bb = idx >> 6, s = idx & 63;
                    const float4 xv = xr[i];
                    bf16x8 pk;
                    pk[0] = (__bf16)xv.x; pk[1] = (__bf16)xv.y;
                    pk[2] = (__bf16)xv.z; pk[3] = (__bf16)xv.w;
                    pk[4] = (__bf16)(xv.x - (float)pk[0]);
                    pk[5] = (__bf16)(xv.y - (float)pk[1]);
                    pk[6] = (__bf16)(xv.z - (float)pk[2]);
                    pk[7] = (__bf16)(xv.w - (float)pk[3]);
                    *reinterpret_cast<bf16x8*>(&xbuf[bb][s][0]) = pk;
                }
            }
        }
        __syncthreads();   // final h (pingpong 0, T even) published

        // ---- linear head: out[b][bin] = h[b]·lw[bin] + lb[bin] ----
        {
            const int m = tid & 15, up = tid >> 4;
            const float* lwb = lw + bin * HID;
            float s = 0.0f;
            #pragma unroll
            for (int e = 0; e < 4; ++e) {
                const int uu = up * 4 + e;
                s = fmaf((float)hbuf[0][0][m][uu] + (float)hbuf[0][1][m][uu], lwb[uu], s);
            }
            part[tid] = s;
            __syncthreads();
            if (tid < 16) {
                float v = lb[bin];
                #pragma unroll
                for (int j = 0; j < 16; ++j) v += part[j * 16 + tid];
                out[(size_t)(b0 + tid) * NB + bin] = v;
            }
            __syncthreads();   // before LDS reuse by next bin
        }
    }
}

extern "C" void kernel_launch(void* const* d_in, const int* in_sizes, int n_in,
                              void* d_out, int out_size, void* d_ws, size_t ws_size,
                              hipStream_t stream) {
    const float* X   = (const float*)d_in[0];
    const float* cw  = (const float*)d_in[1];
    const float* cb  = (const float*)d_in[2];
    const float* wih = (const float*)d_in[3];
    const float* whh = (const float*)d_in[4];
    const float* bih = (const float*)d_in[5];
    const float* bhh = (const float*)d_in[6];
    const float* lw  = (const float*)d_in[7];
    const float* lb  = (const float*)d_in[8];
    float* out = (float*)d_out;
    float* xc  = (float*)d_ws;   // 7,864,320 floats = 31.5 MB

    pool_conv_kernel<<<BATCH, 256, 0, stream>>>(X, cw, cb, xc);
    lstm_mfma_kernel<<<256, 256, 0, stream>>>(xc, wih, whh, bih, bhh, lw, lb, out);
}

// Round 10
// 360.752 us; speedup vs baseline: 1.5358x; 1.1547x over previous
//
#include <hip/hip_runtime.h>
#include <math.h>

#define BATCH 2048
#define CIN 14
#define LEN 2048
#define NB 4
#define HID 64
#define NEG 0.01f
#define L2E 1.44269504088896f

typedef __attribute__((ext_vector_type(8))) __bf16 bf16x8;
typedef __attribute__((ext_vector_type(4))) float f32x4;

// ---------------- Kernel A: pool (hierarchical) + conv1d(k=3,pad=1) + LeakyReLU ----------------
__device__ __forceinline__ void conv_bin(const float* __restrict__ P, int ldp, int T,
                                         int bin,
                                         const float* __restrict__ cw,
                                         const float* __restrict__ cb,
                                         float* __restrict__ dst, int tid)
{
    const float* w = cw + (size_t)bin * 4 * CIN * 3;
    const float b0 = cb[bin * 4 + 0];
    const float b1 = cb[bin * 4 + 1];
    const float b2 = cb[bin * 4 + 2];
    const float b3 = cb[bin * 4 + 3];
    for (int t = tid; t < T; t += 256) {
        float a0 = b0, a1 = b1, a2 = b2, a3 = b3;
        for (int ci = 0; ci < CIN; ++ci) {
            float pm = (t > 0)     ? P[ci * ldp + t - 1] : 0.0f;
            float p0 =               P[ci * ldp + t];
            float pp = (t < T - 1) ? P[ci * ldp + t + 1] : 0.0f;
            const float* w0 = w + (0 * CIN + ci) * 3;
            const float* w1 = w + (1 * CIN + ci) * 3;
            const float* w2 = w + (2 * CIN + ci) * 3;
            const float* w3 = w + (3 * CIN + ci) * 3;
            a0 += w0[0] * pm + w0[1] * p0 + w0[2] * pp;
            a1 += w1[0] * pm + w1[1] * p0 + w1[2] * pp;
            a2 += w2[0] * pm + w2[1] * p0 + w2[2] * pp;
            a3 += w3[0] * pm + w3[1] * p0 + w3[2] * pp;
        }
        a0 = (a0 >= 0.0f) ? a0 : NEG * a0;
        a1 = (a1 >= 0.0f) ? a1 : NEG * a1;
        a2 = (a2 >= 0.0f) ? a2 : NEG * a2;
        a3 = (a3 >= 0.0f) ? a3 : NEG * a3;
        *reinterpret_cast<float4*>(dst + (size_t)t * 4) = make_float4(a0, a1, a2, a3);
    }
}

__global__ __launch_bounds__(256) void pool_conv_kernel(
    const float* __restrict__ X, const float* __restrict__ cw,
    const float* __restrict__ cb, float* __restrict__ xc)
{
    __shared__ float Pa[CIN][512];
    __shared__ float Pb[CIN][256];
    const int b = blockIdx.x;
    const int tid = threadIdx.x;

    for (int idx = tid; idx < CIN * 512; idx += 256) {
        int c = idx >> 9, t = idx & 511;
        const float4 v = *reinterpret_cast<const float4*>(X + ((size_t)b * CIN + c) * LEN + 4 * t);
        Pa[c][t] = 0.25f * (v.x + v.y + v.z + v.w);
    }
    __syncthreads();

    conv_bin(&Pa[0][0], 512, 512, 0, cw, cb, xc + (size_t)b * 512 * 4, tid);
    for (int idx = tid; idx < CIN * 256; idx += 256) {
        int c = idx >> 8, t = idx & 255;
        Pb[c][t] = 0.5f * (Pa[c][2 * t] + Pa[c][2 * t + 1]);
    }
    __syncthreads();

    conv_bin(&Pb[0][0], 256, 256, 1, cw, cb, xc + 4194304 + (size_t)b * 256 * 4, tid);
    for (int idx = tid; idx < CIN * 128; idx += 256) {
        int c = idx >> 7, t = idx & 127;
        Pa[c][t] = 0.5f * (Pb[c][2 * t] + Pb[c][2 * t + 1]);
    }
    __syncthreads();

    conv_bin(&Pa[0][0], 512, 128, 2, cw, cb, xc + 6291456 + (size_t)b * 128 * 4, tid);
    for (int idx = tid; idx < CIN * 64; idx += 256) {
        int c = idx >> 6, t = idx & 63;
        Pb[c][t] = 0.5f * (Pa[c][2 * t] + Pa[c][2 * t + 1]);
    }
    __syncthreads();

    conv_bin(&Pb[0][0], 256, 64, 3, cw, cb, xc + 7340032 + (size_t)b * 64 * 4, tid);
}

// ---------------- Kernel B: MFMA LSTM scan + linear head ----------------
// r9 structure (4 waves x 16 batch, wave = unit quadrant, 1 barrier/step) with the
// per-step schedule software-pipelined at gate granularity:
//   gate order G,I,F,O; 4 x-MFMAs issued first (cover h ds_read latency); gate g's
//   activations placed between gate g+1/g+2 MFMA chains so trans/VALU overlap the
//   MFMA pipe; only O's trans + c-chain are exposed at the tail.
// Merged-rcp activations: ig=(G-1)/((1+Ei)(G+1)), h=(C2-1)/((1+Eo)(C2+1)):
//   5 exp2 + 3 rcp per row (32 trans/step vs 40), clamps only on acc_g and c upper.
// xf read unconditionally (B-frag rows 8..31 are zero -> lg!=0 lanes contribute 0).

__global__ __launch_bounds__(256)
__attribute__((amdgpu_waves_per_eu(1, 1)))
void lstm_mfma_kernel(
    const float* __restrict__ xc,
    const float* __restrict__ wih, const float* __restrict__ whh,
    const float* __restrict__ bih, const float* __restrict__ bhh,
    const float* __restrict__ lw, const float* __restrict__ lb,
    float* __restrict__ out)
{
    __shared__ __bf16 hbuf[2][2][16][80];   // [pingpong][hi/lo][row][unit]
    __shared__ __bf16 xbuf[16][65][8];      // [batch][step][xhi(4)|xlo(4)]
    __shared__ float  part[256];

    const int tid = threadIdx.x;
    const int w   = tid >> 6;        // wave = unit quadrant
    const int l   = tid & 63;
    const int lm  = l & 15;
    const int lg  = l >> 4;

    const int TS[NB]     = {512, 256, 128, 64};
    const size_t OFF[NB] = {0, 4194304, 6291456, 7340032};

    const bool isBin0 = (blockIdx.x < 128);
    const int b0   = (isBin0 ? blockIdx.x : (blockIdx.x - 128)) * 16;
    const int binS = isBin0 ? 0 : 1;
    const int binE = isBin0 ? 1 : 4;

    for (int bin = binS; bin < binE; ++bin) {
        const int T = TS[bin];
        const int NW = T >> 6;
        const float* xbase = xc + OFF[bin];

        // ---- weights: Whh split fragments + Wih x-tile B-frag + bias, exp2-prescaled ----
        // gate index order in arrays: 0=G(tanh, +2L2E), 1=I, 2=F, 3=O (all -L2E)
        bf16x8 whiF[4][2], wloF[4][2], xwB[4];
        float  bias[4];
        const int GMAP[4] = {2, 0, 1, 3};   // array slot -> reference gate row block
        #pragma unroll
        for (int gs = 0; gs < 4; ++gs) {
            const int gate = GMAP[gs];
            const float sc = (gate == 2) ? (2.0f * L2E) : (-L2E);
            const int col = bin * 256 + gate * 64 + w * 16 + lm;
            const float* wr = whh + (size_t)col * 64;
            #pragma unroll
            for (int kt = 0; kt < 2; ++kt) {
                const float* p = wr + kt * 32 + lg * 8;
                const float4 u0 = *reinterpret_cast<const float4*>(p);
                const float4 u1 = *reinterpret_cast<const float4*>(p + 4);
                const float v[8] = {sc * u0.x, sc * u0.y, sc * u0.z, sc * u0.w,
                                    sc * u1.x, sc * u1.y, sc * u1.z, sc * u1.w};
                bf16x8 hi8, lo8;
                #pragma unroll
                for (int e = 0; e < 8; ++e) {
                    const __bf16 hb = (__bf16)v[e];
                    hi8[e] = hb;
                    lo8[e] = (__bf16)(v[e] - (float)hb);
                }
                whiF[gs][kt] = hi8;
                wloF[gs][kt] = lo8;
            }
            const float4 wiv = *reinterpret_cast<const float4*>(wih + (size_t)col * 4);
            bf16x8 xw;
            xw[0] = (__bf16)(sc * wiv.x); xw[1] = (__bf16)(sc * wiv.y);
            xw[2] = (__bf16)(sc * wiv.z); xw[3] = (__bf16)(sc * wiv.w);
            xw[4] = xw[0]; xw[5] = xw[1]; xw[6] = xw[2]; xw[7] = xw[3];
            if (lg != 0) {
                #pragma unroll
                for (int e = 0; e < 8; ++e) xw[e] = (__bf16)0.0f;
            }
            xwB[gs] = xw;
            bias[gs] = (bih[col] + bhh[col]) * sc;
        }

        // ---- prologue: window 0 -> xbuf; zero h pingpong 0 ----
        #pragma unroll
        for (int i = 0; i < 4; ++i) {
            const int idx = tid + i * 256;
            const int bb = idx >> 6, s = idx & 63;
            const float4 xv = *reinterpret_cast<const float4*>(
                xbase + ((size_t)(b0 + bb) * T + s) * 4);
            bf16x8 pk;
            pk[0] = (__bf16)xv.x; pk[1] = (__bf16)xv.y;
            pk[2] = (__bf16)xv.z; pk[3] = (__bf16)xv.w;
            pk[4] = (__bf16)(xv.x - (float)pk[0]);
            pk[5] = (__bf16)(xv.y - (float)pk[1]);
            pk[6] = (__bf16)(xv.z - (float)pk[2]);
            pk[7] = (__bf16)(xv.w - (float)pk[3]);
            *reinterpret_cast<bf16x8*>(&xbuf[bb][s][0]) = pk;
        }
        {
            __bf16* hz = &hbuf[0][0][0][0];
            #pragma unroll
            for (int i = 0; i < 10; ++i) hz[tid + i * 256] = (__bf16)0.0f;
        }
        float c4[4] = {0.0f, 0.0f, 0.0f, 0.0f};

        for (int tb = 0; tb < NW; ++tb) {
            float4 xr[4];
            #pragma unroll 2
            for (int tw = 0; tw < 64; ++tw) {
                if (tw == 32 && tb + 1 < NW) {
                    #pragma unroll
                    for (int i = 0; i < 4; ++i) {
                        const int idx = tid + i * 256;
                        const int bb = idx >> 6, s = idx & 63;
                        xr[i] = *reinterpret_cast<const float4*>(
                            xbase + ((size_t)(b0 + bb) * T + (tb + 1) * 64 + s) * 4);
                    }
                }
                __syncthreads();   // h(t-1) + x window visible

                const int pp = tw & 1, pq = pp ^ 1;   // compile-time under unroll 2

                // all loads issued up front; xf unconditional (broadcast per lm)
                const bf16x8 xfv = *reinterpret_cast<const bf16x8*>(&xbuf[lm][tw][0]);
                const bf16x8 zhi0 = *reinterpret_cast<const bf16x8*>(&hbuf[pp][0][lm][lg * 8]);
                const bf16x8 zhi1 = *reinterpret_cast<const bf16x8*>(&hbuf[pp][0][lm][32 + lg * 8]);
                const bf16x8 zlo0 = *reinterpret_cast<const bf16x8*>(&hbuf[pp][1][lm][lg * 8]);
                const bf16x8 zlo1 = *reinterpret_cast<const bf16x8*>(&hbuf[pp][1][lm][32 + lg * 8]);

                // 4 x-MFMAs first (only need xfv -> cover h ds_read latency)
                f32x4 aG = {bias[0], bias[0], bias[0], bias[0]};
                f32x4 aI = {bias[1], bias[1], bias[1], bias[1]};
                f32x4 aF = {bias[2], bias[2], bias[2], bias[2]};
                f32x4 aO = {bias[3], bias[3], bias[3], bias[3]};
                aG = __builtin_amdgcn_mfma_f32_16x16x32_bf16(xfv, xwB[0], aG, 0, 0, 0);
                aI = __builtin_amdgcn_mfma_f32_16x16x32_bf16(xfv, xwB[1], aI, 0, 0, 0);
                aF = __builtin_amdgcn_mfma_f32_16x16x32_bf16(xfv, xwB[2], aF, 0, 0, 0);
                aO = __builtin_amdgcn_mfma_f32_16x16x32_bf16(xfv, xwB[3], aO, 0, 0, 0);

                // G chain (6), then I chain (6)
                aG = __builtin_amdgcn_mfma_f32_16x16x32_bf16(zhi0, whiF[0][0], aG, 0, 0, 0);
                aG = __builtin_amdgcn_mfma_f32_16x16x32_bf16(zhi1, whiF[0][1], aG, 0, 0, 0);
                aG = __builtin_amdgcn_mfma_f32_16x16x32_bf16(zlo0, whiF[0][0], aG, 0, 0, 0);
                aG = __builtin_amdgcn_mfma_f32_16x16x32_bf16(zlo1, whiF[0][1], aG, 0, 0, 0);
                aG = __builtin_amdgcn_mfma_f32_16x16x32_bf16(zhi0, wloF[0][0], aG, 0, 0, 0);
                aG = __builtin_amdgcn_mfma_f32_16x16x32_bf16(zhi1, wloF[0][1], aG, 0, 0, 0);

                aI = __builtin_amdgcn_mfma_f32_16x16x32_bf16(zhi0, whiF[1][0], aI, 0, 0, 0);
                aI = __builtin_amdgcn_mfma_f32_16x16x32_bf16(zhi1, whiF[1][1], aI, 0, 0, 0);
                aI = __builtin_amdgcn_mfma_f32_16x16x32_bf16(zlo0, whiF[1][0], aI, 0, 0, 0);
                aI = __builtin_amdgcn_mfma_f32_16x16x32_bf16(zlo1, whiF[1][1], aI, 0, 0, 0);
                aI = __builtin_amdgcn_mfma_f32_16x16x32_bf16(zhi0, wloF[1][0], aI, 0, 0, 0);
                aI = __builtin_amdgcn_mfma_f32_16x16x32_bf16(zhi1, wloF[1][1], aI, 0, 0, 0);

                // G exp2s (overlap F chain issue below)
                float eG[4];
                #pragma unroll
                for (int r = 0; r < 4; ++r)
                    eG[r] = __builtin_amdgcn_exp2f(fminf(aG[r], 120.0f));

                // F chain (6)
                aF = __builtin_amdgcn_mfma_f32_16x16x32_bf16(zhi0, whiF[2][0], aF, 0, 0, 0);
                aF = __builtin_amdgcn_mfma_f32_16x16x32_bf16(zhi1, whiF[2][1], aF, 0, 0, 0);
                aF = __builtin_amdgcn_mfma_f32_16x16x32_bf16(zlo0, whiF[2][0], aF, 0, 0, 0);
                aF = __builtin_amdgcn_mfma_f32_16x16x32_bf16(zlo1, whiF[2][1], aF, 0, 0, 0);
                aF = __builtin_amdgcn_mfma_f32_16x16x32_bf16(zhi0, wloF[2][0], aF, 0, 0, 0);
                aF = __builtin_amdgcn_mfma_f32_16x16x32_bf16(zhi1, wloF[2][1], aF, 0, 0, 0);

                // I exp2s + merged i*tanh(g) (overlap O chain issue below)
                float rig[4];
                #pragma unroll
                for (int r = 0; r < 4; ++r) {
                    const float eI = __builtin_amdgcn_exp2f(aI[r]);
                    rig[r] = (eG[r] - 1.0f) *
                             __builtin_amdgcn_rcpf((1.0f + eI) * (eG[r] + 1.0f));
                }

                // O chain (6)
                aO = __builtin_amdgcn_mfma_f32_16x16x32_bf16(zhi0, whiF[3][0], aO, 0, 0, 0);
                aO = __builtin_amdgcn_mfma_f32_16x16x32_bf16(zhi1, whiF[3][1], aO, 0, 0, 0);
                aO = __builtin_amdgcn_mfma_f32_16x16x32_bf16(zlo0, whiF[3][0], aO, 0, 0, 0);
                aO = __builtin_amdgcn_mfma_f32_16x16x32_bf16(zlo1, whiF[3][1], aO, 0, 0, 0);
                aO = __builtin_amdgcn_mfma_f32_16x16x32_bf16(zhi0, wloF[3][0], aO, 0, 0, 0);
                aO = __builtin_amdgcn_mfma_f32_16x16x32_bf16(zhi1, wloF[3][1], aO, 0, 0, 0);

                // F sigmoid + c update (overlaps O chain tail)
                #pragma unroll
                for (int r = 0; r < 4; ++r) {
                    const float eF = __builtin_amdgcn_exp2f(aF[r]);
                    c4[r] = fmaf(__builtin_amdgcn_rcpf(1.0f + eF), c4[r], rig[r]);
                }

                // O + tanh(c) merged; h write (exposed tail)
                const int u = w * 16 + lm;
                #pragma unroll
                for (int r = 0; r < 4; ++r) {
                    const float eO = __builtin_amdgcn_exp2f(aO[r]);
                    const float C2 = __builtin_amdgcn_exp2f(
                        fminf((2.0f * L2E) * c4[r], 120.0f));
                    const float hv = (C2 - 1.0f) *
                        __builtin_amdgcn_rcpf((1.0f + eO) * (C2 + 1.0f));
                    const int row = lg * 4 + r;
                    const __bf16 hb = (__bf16)hv;
                    hbuf[pq][0][row][u] = hb;
                    hbuf[pq][1][row][u] = (__bf16)(hv - (float)hb);
                }
            }
            if (tb + 1 < NW) {
                __syncthreads();   // all reads of this x window done
                #pragma unroll
                for (int i = 0; i < 4; ++i) {
                    const int idx = tid + i * 256;
                    const int bb = idx >> 6, s = idx & 63;
                    const float4 xv = xr[i];
                    bf16x8 pk;
                    pk[0] = (__bf16)xv.x; pk[1] = (__bf16)xv.y;
                    pk[2] = (__bf16)xv.z; pk[3] = (__bf16)xv.w;
                    pk[4] = (__bf16)(xv.x - (float)pk[0]);
                    pk[5] = (__bf16)(xv.y - (float)pk[1]);
                    pk[6] = (__bf16)(xv.z - (float)pk[2]);
                    pk[7] = (__bf16)(xv.w - (float)pk[3]);
                    *reinterpret_cast<bf16x8*>(&xbuf[bb][s][0]) = pk;
                }
            }
        }
        __syncthreads();   // final h (pingpong 0, T even) published

        // ---- linear head: out[b][bin] = h[b]·lw[bin] + lb[bin] ----
        {
            const int m = tid & 15, up = tid >> 4;
            const float* lwb = lw + bin * HID;
            float s = 0.0f;
            #pragma unroll
            for (int e = 0; e < 4; ++e) {
                const int uu = up * 4 + e;
                s = fmaf((float)hbuf[0][0][m][uu] + (float)hbuf[0][1][m][uu], lwb[uu], s);
            }
            part[tid] = s;
            __syncthreads();
            if (tid < 16) {
                float v = lb[bin];
                #pragma unroll
                for (int j = 0; j < 16; ++j) v += part[j * 16 + tid];
                out[(size_t)(b0 + tid) * NB + bin] = v;
            }
            __syncthreads();   // before LDS reuse by next bin
        }
    }
}

extern "C" void kernel_launch(void* const* d_in, const int* in_sizes, int n_in,
                              void* d_out, int out_size, void* d_ws, size_t ws_size,
                              hipStream_t stream) {
    const float* X   = (const float*)d_in[0];
    const float* cw  = (const float*)d_in[1];
    const float* cb  = (const float*)d_in[2];
    const float* wih = (const float*)d_in[3];
    const float* whh = (const float*)d_in[4];
    const float* bih = (const float*)d_in[5];
    const float* bhh = (const float*)d_in[6];
    const float* lw  = (const float*)d_in[7];
    const float* lb  = (const float*)d_in[8];
    float* out = (float*)d_out;
    float* xc  = (float*)d_ws;   // 7,864,320 floats = 31.5 MB

    pool_conv_kernel<<<BATCH, 256, 0, stream>>>(X, cw, cb, xc);
    lstm_mfma_kernel<<<256, 256, 0, stream>>>(xc, wih, whh, bih, bhh, lw, lb, out);
}